// Round 7
// baseline (138.704 us; speedup 1.0000x reference)
//
#include <hip/hip_runtime.h>
#include <math.h>

#define NB 16
#define NC 80
#define HH 128
#define WW 128
#define NOBJ 100
#define HW (HH*WW)
#define SCATTER_BLOCKS (NB*NOBJ)                  // 1600
#define F4_TOTAL (NB*NC*HW/4)                     // 5,242,880 float4s
#define F4_PER_BLOCK (256*8)                      // 2048
#define DENSE_BLOCKS (F4_TOTAL/F4_PER_BLOCK)      // 2560
#define TOTAL_BLOCKS (SCATTER_BLOCKS + DENSE_BLOCKS)   // 4160 = 13*320; 1600/4160 = 5/13

typedef __attribute__((ext_vector_type(4))) float f4;

// ws layout (doubles, every slot written every launch -> poison-safe, no memset):
//  part[0 .. DENSE_BLOCKS)                      dense negl partial per dense block
//  part[DENSE_BLOCKS + s*5 + k], k=0..4         scatter partials: posl, negl_corr, npos, wsum, giou
#define SACC_OFF DENSE_BLOCKS

// ---------------- Kernel 1: interleaved scatter + dense focal baseline ----------
__global__ __launch_bounds__(256, 4) void main_kernel(const float* __restrict__ heat,
                                                      const float* __restrict__ wh,
                                                      const float* __restrict__ ann,
                                                      double* __restrict__ part) {
    // interleave: of every 13 consecutive blocks, 5 are scatter, 8 are dense
    int grp = blockIdx.x / 13;
    int rem = blockIdx.x - grp * 13;
    bool is_scatter = rem < 5;

    if (!is_scatter) {
        // ===== dense path: flat streaming focal baseline (tgt = 0), non-temporal =====
        int db = grp * 8 + (rem - 5);
        const f4* hp = (const f4*)heat;
        size_t base = (size_t)db * F4_PER_BLOCK + threadIdx.x;
        f4 v[8];
        #pragma unroll
        for (int k = 0; k < 8; ++k) v[k] = __builtin_nontemporal_load(hp + base + (size_t)k * 256);
        float n0 = 0.f, n1 = 0.f;
        #pragma unroll
        for (int k = 0; k < 8; ++k) {
            #pragma unroll
            for (int m = 0; m < 4; ++m) {
                float h = v[k][m];
                float e = __expf(-h);
                float q = 1.f + e;
                float lq = __logf(q);
                float p = 1.f / q;
                float t = (h + lq) * p * p;     // -log(1-pred) * pred^2
                if (m & 1) n1 += t; else n0 += t;
            }
        }
        float r = n0 + n1;
        for (int off = 32; off > 0; off >>= 1) r += __shfl_down(r, off, 64);
        __shared__ float dred[4];
        int lane = threadIdx.x & 63, wv = threadIdx.x >> 6;
        if (lane == 0) dred[wv] = r;
        __syncthreads();
        if (threadIdx.x == 0)
            part[db] = (double)dred[0] + (double)dred[1] + (double)dred[2] + (double)dred[3];
        return;
    }

    // ===== scatter path: one block per (image, sorted object), self-contained prep =====
    int sblk = grp * 5 + rem;
    int b = sblk / NOBJ;
    int i = sblk - b * NOBJ;
    double* sacc = part + SACC_OFF + (size_t)sblk * 5;
    int tid = threadIdx.x;

    __shared__ float4 sg0[NOBJ];   // cx, cy, wr, hr
    __shared__ float4 sg1[NOBJ];   // ivx, ivy, cls_bits, ivg
    __shared__ float4 sg2[NOBJ];   // x1, y1, x2, y2
    __shared__ float skey[NOBJ];
    __shared__ int prevl[NOBJ], nextl[NOBJ];
    __shared__ int s_nv, s_np, s_nn;
    if (tid == 0) { s_nv = 0; s_np = 0; s_nn = 0; }

    // ---- phase A0: load annotations, publish keys + valid count
    float x1=0.f, y1=0.f, x2=0.f, y2=0.f, clsv=-1.f;
    float key = INFINITY;            // key = -log_a; invalid -> +inf (sorted last, stable)
    bool on = tid < NOBJ;
    if (on) {
        const float* a = ann + ((size_t)b * NOBJ + tid) * 5;
        x1=a[0]; y1=a[1]; x2=a[2]; y2=a[3]; clsv=a[4];
        if (clsv >= 0.f) {
            float area = (y2 - y1 + 1.f) * (x2 - x1 + 1.f);
            key = -__logf(fmaxf(area, 1e-12f));
            atomicAdd(&s_nv, 1);
        }
        skey[tid] = key;
    }
    __syncthreads();

    int nvb = s_nv;
    if (i >= nvb) {                  // block-uniform early exit before sort/params
        if (tid < 5) sacc[tid] = 0.0;
        return;
    }

    // ---- phase A1: stable rank + per-object params + separable gsum (all in LDS)
    if (on) {
        // stable ascending rank == jnp.argsort(-log_a)
        int r = 0;
        for (int j = 0; j < NOBJ; ++j) {
            float kj = skey[j];
            if (kj < key || (kj == key && j < tid)) r++;
        }
        bool valid = (clsv >= 0.f);

        float cx = truncf((x1 + x2) * 0.125f);       // *0.5/DOWN, DOWN=4
        float cy = truncf((y1 + y2) * 0.125f);
        float fx1 = fminf(fmaxf(x1*0.25f, 0.f), WW - 1.f);
        float fx2 = fminf(fmaxf(x2*0.25f, 0.f), WW - 1.f);
        float fy1 = fminf(fmaxf(y1*0.25f, 0.f), HH - 1.f);
        float fy2 = fminf(fmaxf(y2*0.25f, 0.f), HH - 1.f);
        int hr = (int)((fy2 - fy1) * 0.5f * 0.54f);  // trunc matches astype(int32)
        int wr = (int)((fx2 - fx1) * 0.5f * 0.54f);
        float sx = (float)(2*wr + 1) / 6.0f;
        float sy = (float)(2*hr + 1) / 6.0f;
        float ivx = 1.f / (2.f * sx * sx);
        float ivy = 1.f / (2.f * sy * sy);

        // separable gaussian sum (gx carries the valid mask, as in reference)
        int yc = (int)cy, xc = (int)cx;
        float sgy = 0.f;
        {
            int ya = max(0, yc - hr), yb = min(HH - 1, yc + hr);
            for (int y = ya; y <= yb; ++y) {
                float dy = (float)y - cy;
                sgy += __expf(-(dy*dy) * ivy);
            }
        }
        float sgx = 0.f;
        if (valid) {
            int xa = max(0, xc - wr), xb = min(WW - 1, xc + wr);
            for (int x = xa; x <= xb; ++x) {
                float dx = (float)x - cx;
                sgx += __expf(-(dx*dx) * ivx);
            }
        }
        float gsum = fmaxf(sgy * sgx, 1e-12f);
        int cls_i = min(max((int)clsv, 0), NC - 1);

        sg0[r] = make_float4(cx, cy, (float)wr, (float)hr);
        sg1[r] = make_float4(ivx, ivy, __int_as_float(cls_i), 1.f / gsum);
        sg2[r] = make_float4(x1, y1, x2, y2);
    }
    __syncthreads();

    float4 g0i = sg0[i], g1i = sg1[i], g2i = sg2[i];
    float cx = g0i.x, cy = g0i.y;
    int wr = (int)g0i.z, hr = (int)g0i.w;
    float ivx = g1i.x, ivy = g1i.y;
    int ci = __float_as_int(g1i.z);
    float ivg = g1i.w;
    int xc = (int)cx, yc = (int)cy;
    int xa = max(0, xc - wr), xb = min(WW - 1, xc + wr);
    int ya = max(0, yc - hr), yb = min(HH - 1, yc + hr);
    int wN = xb - xa + 1, hN = yb - ya + 1, npix = wN * hN;

    // ---- candidate lists: objects whose (unclipped) window intersects mine ----
    if (tid < nvb && tid != i) {
        float4 g0 = sg0[tid];
        bool inter = (g0.x - g0.z <= (float)xb) && (g0.x + g0.z >= (float)xa) &&
                     (g0.y - g0.w <= (float)yb) && (g0.y + g0.w >= (float)ya);
        if (inter) {
            int cj = __float_as_int(sg1[tid].z);
            if (tid < i) {
                if (cj == ci) prevl[atomicAdd(&s_np, 1)] = tid;
            } else {
                nextl[atomicAdd(&s_nn, 1)] = tid | ((cj == ci) ? 0x10000 : 0);
            }
        }
    }
    __syncthreads();
    int np = s_np, nn = s_nn;

    float posl = 0.f, negl = 0.f, npos = 0.f, wsum = 0.f, gl = 0.f;

    for (int t0 = tid; t0 < npix; t0 += 256) {   // npix <= 225 here: single iteration
        int ry = t0 / wN;
        int px = xa + (t0 - ry * wN);
        int py = ya + ry;
        float fx = (float)px, fy = (float)py;

        // first covering object of class ci at this pixel? (order-free existence)
        bool first = true;
        for (int k = 0; k < np; ++k) {
            float4 g0 = sg0[prevl[k]];
            if (fabsf(fx - g0.x) <= g0.z && fabsf(fy - g0.y) <= g0.w) first = false;
        }

        float dxi = fx - cx, dyi = fy - cy;
        float gi = __expf(-(dxi*dxi) * ivx) * __expf(-(dyi*dyi) * ivy);
        float t = gi;
        bool is_owner = true;        // owner = largest covering sorted idx
        for (int k = 0; k < nn; ++k) {
            int e = nextl[k];
            int j = e & 0xFFFF;
            float4 g0 = sg0[j];
            float dxj = fx - g0.x, dyj = fy - g0.y;
            if (fabsf(dxj) <= g0.z && fabsf(dyj) <= g0.w) {
                is_owner = false;
                if ((e & 0x10000) && first) {
                    float4 g1 = sg1[j];
                    float gj = __expf(-(dxj*dxj) * g1.x) * __expf(-(dyj*dyj) * g1.y);
                    t = fmaxf(t, gj);
                }
            }
        }

        if (first) {
            // correction vs. dense tgt=0 baseline for (pixel, class ci)
            float h = heat[((size_t)b * NC + ci) * HW + (size_t)py * WW + px];
            float e = __expf(-h);
            float q = 1.f + e;
            float lq = __logf(q);
            float p = 1.f / q;
            float basef = (h + lq) * p * p;
            if (t == 1.0f) {
                posl += lq * (1.f - p) * (1.f - p);   // -log(pred)*(1-pred)^2
                negl -= basef;
                npos += 1.f;
            } else {
                float u1 = 1.f - t;
                float u2 = u1 * u1;
                negl += basef * (u2 * u2 - 1.f);      // weight (1-t)^4 instead of 1
            }
        }

        if (is_owner) {
            float w = gi * ivg;
            size_t po = (size_t)py * WW + px;
            const float* whb = wh + (size_t)b * 4 * HW + po;
            float w0 = whb[0], w1 = whb[HW], w2 = whb[2*HW], w3 = whb[3*HW];
            float bx = fx * 4.f, by = fy * 4.f;
            float px1 = bx - w0, py1 = by - w1, px2 = bx + w2, py2 = by + w3;
            float tx1 = g2i.x, ty1 = g2i.y, tx2 = g2i.z, ty2 = g2i.w;
            float ltx = fmaxf(px1, tx1), lty = fmaxf(py1, ty1);
            float rbx = fminf(px2, tx2), rby = fminf(py2, ty2);
            float iw = fmaxf(rbx - ltx + 1.f, 0.f), ih = fmaxf(rby - lty + 1.f, 0.f);
            float e1x = fminf(px1, tx1), e1y = fminf(py1, ty1);
            float e2x = fmaxf(px2, tx2), e2y = fmaxf(py2, ty2);
            float ew = fmaxf(e2x - e1x + 1.f, 0.f), eh = fmaxf(e2y - e1y + 1.f, 0.f);
            float ov = iw * ih;
            float ap = (px2 - px1 + 1.f) * (py2 - py1 + 1.f);
            float ag = (tx2 - tx1 + 1.f) * (ty2 - ty1 + 1.f);
            float u = ap + ag - ov;
            float iou = ov / u;
            float ea = ew * eh;
            float giou = iou - (ea - u) / ea;
            wsum += w;
            gl += (1.f - giou) * w;
        }
    }

    // reduce 5 values over 4 waves -> plain stores to this block's unique slot
    float vals[5] = { posl, negl, npos, wsum, gl };
    #pragma unroll
    for (int k = 0; k < 5; ++k) {
        float v = vals[k];
        for (int off = 32; off > 0; off >>= 1) v += __shfl_down(v, off, 64);
        vals[k] = v;
    }
    __shared__ float red[5][4];
    int lane = tid & 63, wv = tid >> 6;
    if (lane == 0) {
        #pragma unroll
        for (int k = 0; k < 5; ++k) red[k][wv] = vals[k];
    }
    __syncthreads();
    if (tid == 0) {
        #pragma unroll
        for (int k = 0; k < 5; ++k)
            sacc[k] = (double)red[k][0] + (double)red[k][1] + (double)red[k][2] + (double)red[k][3];
    }
}

// ---------------- Kernel 2: finalize (parallel reduction over all partials) ----------
__global__ __launch_bounds__(512) void finalize_kernel(const double* __restrict__ part,
                                                       float* __restrict__ out) {
    int tid = threadIdx.x;
    double v[6] = {0,0,0,0,0,0};     // dneg, posl, negc, npos, wsum, gl
    for (int d = tid; d < DENSE_BLOCKS; d += 512) v[0] += part[d];
    for (int s = tid; s < SCATTER_BLOCKS; s += 512) {
        const double* p = part + SACC_OFF + (size_t)s * 5;
        v[1] += p[0]; v[2] += p[1]; v[3] += p[2]; v[4] += p[3]; v[5] += p[4];
    }
    #pragma unroll
    for (int k = 0; k < 6; ++k) {
        double x = v[k];
        for (int off = 32; off > 0; off >>= 1) x += __shfl_down(x, off, 64);
        v[k] = x;
    }
    __shared__ double red[6][8];
    int lane = tid & 63, wv = tid >> 6;
    if (lane == 0) {
        #pragma unroll
        for (int k = 0; k < 6; ++k) red[k][wv] = v[k];
    }
    __syncthreads();
    if (tid == 0) {
        double s[6];
        #pragma unroll
        for (int k = 0; k < 6; ++k) {
            double x = 0.0;
            for (int w = 0; w < 8; ++w) x += red[k][w];
            s[k] = x;
        }
        double neg = s[2] + s[0];
        double hm = (s[3] > 0.0) ? (s[1] + neg) / s[3] : neg;
        out[0] = (float)hm;                           // HM_W = 1.0
        out[1] = (float)(s[5] / (s[4] + 1e-4) * 0.1); // WH_W = 0.1
    }
}

extern "C" void kernel_launch(void* const* d_in, const int* in_sizes, int n_in,
                              void* d_out, int out_size, void* d_ws, size_t ws_size,
                              hipStream_t stream) {
    const float* heat = (const float*)d_in[0];   // (16,80,128,128)
    const float* wh   = (const float*)d_in[1];   // (16,4,128,128)
    const float* ann  = (const float*)d_in[2];   // (16,100,5)
    float* out = (float*)d_out;

    double* part = (double*)d_ws;

    main_kernel<<<TOTAL_BLOCKS, 256, 0, stream>>>(heat, wh, ann, part);
    finalize_kernel<<<1, 512, 0, stream>>>(part, out);
}

// Round 8
// 134.866 us; speedup vs baseline: 1.0285x; 1.0285x over previous
//
#include <hip/hip_runtime.h>
#include <math.h>

#define NB 16
#define NC 80
#define HH 128
#define WW 128
#define NOBJ 100
#define HW (HH*WW)
#define SCATTER_BLOCKS (NB*NOBJ)                  // 1600
#define F4_TOTAL (NB*NC*HW/4)                     // 5,242,880 float4s
#define F4_PER_BLOCK (256*8)                      // 2048
#define DENSE_BLOCKS (F4_TOTAL/F4_PER_BLOCK)      // 2560
#define TOTAL_BLOCKS (SCATTER_BLOCKS + DENSE_BLOCKS)   // 4160 = 13*320; 1600/4160 = 5/13

// ws layout (doubles, every slot written every launch -> poison-safe, no memset):
//  part[0 .. DENSE_BLOCKS)                      dense negl partial per dense block
//  part[DENSE_BLOCKS + s*5 + k], k=0..4         scatter partials: posl, negl_corr, npos, wsum, giou
#define SACC_OFF DENSE_BLOCKS

// ---------------- Kernel 1: interleaved scatter + dense focal baseline ----------
__global__ __launch_bounds__(256, 4) void main_kernel(const float* __restrict__ heat,
                                                      const float* __restrict__ wh,
                                                      const float* __restrict__ ann,
                                                      double* __restrict__ part) {
    // interleave: of every 13 consecutive blocks, 5 are scatter, 8 are dense
    int grp = blockIdx.x / 13;
    int rem = blockIdx.x - grp * 13;
    bool is_scatter = rem < 5;

    if (!is_scatter) {
        // ===== dense path: flat streaming focal baseline (tgt = 0) =====
        // NOTE: plain cached loads — the input-restore leaves heat hot in LLC;
        // nontemporal loads regressed 131->139 us (round 7).
        int db = grp * 8 + (rem - 5);
        const float4* hp = (const float4*)heat;
        size_t base = (size_t)db * F4_PER_BLOCK + threadIdx.x;
        float4 v[8];
        #pragma unroll
        for (int k = 0; k < 8; ++k) v[k] = hp[base + (size_t)k * 256];
        float n0 = 0.f, n1 = 0.f;
        #pragma unroll
        for (int k = 0; k < 8; ++k) {
            float hv[4] = { v[k].x, v[k].y, v[k].z, v[k].w };
            #pragma unroll
            for (int m = 0; m < 4; ++m) {
                float h = hv[m];
                float e = __expf(-h);
                float q = 1.f + e;
                float lq = __logf(q);
                float p = 1.f / q;
                float t = (h + lq) * p * p;     // -log(1-pred) * pred^2
                if (m & 1) n1 += t; else n0 += t;
            }
        }
        float r = n0 + n1;
        for (int off = 32; off > 0; off >>= 1) r += __shfl_down(r, off, 64);
        __shared__ float dred[4];
        int lane = threadIdx.x & 63, wv = threadIdx.x >> 6;
        if (lane == 0) dred[wv] = r;
        __syncthreads();
        if (threadIdx.x == 0)
            part[db] = (double)dred[0] + (double)dred[1] + (double)dred[2] + (double)dred[3];
        return;
    }

    // ===== scatter path: one block per (image, sorted object), self-contained prep =====
    int sblk = grp * 5 + rem;
    int b = sblk / NOBJ;
    int i = sblk - b * NOBJ;
    double* sacc = part + SACC_OFF + (size_t)sblk * 5;
    int tid = threadIdx.x;

    __shared__ float4 sg0[NOBJ];   // cx, cy, wr, hr
    __shared__ float4 sg1[NOBJ];   // ivx, ivy, cls_bits, ivg
    __shared__ float4 sg2[NOBJ];   // x1, y1, x2, y2
    __shared__ float skey[NOBJ];
    __shared__ int prevl[NOBJ], nextl[NOBJ];
    __shared__ int s_nv, s_np, s_nn;
    if (tid == 0) { s_nv = 0; s_np = 0; s_nn = 0; }

    // ---- phase A0: load annotations, publish keys + valid count
    float x1=0.f, y1=0.f, x2=0.f, y2=0.f, clsv=-1.f;
    float key = INFINITY;            // key = -log_a; invalid -> +inf (sorted last, stable)
    bool on = tid < NOBJ;
    if (on) {
        const float* a = ann + ((size_t)b * NOBJ + tid) * 5;
        x1=a[0]; y1=a[1]; x2=a[2]; y2=a[3]; clsv=a[4];
        if (clsv >= 0.f) {
            float area = (y2 - y1 + 1.f) * (x2 - x1 + 1.f);
            key = -__logf(fmaxf(area, 1e-12f));
            atomicAdd(&s_nv, 1);
        }
        skey[tid] = key;
    }
    __syncthreads();

    int nvb = s_nv;
    if (i >= nvb) {                  // block-uniform early exit before sort/params
        if (tid < 5) sacc[tid] = 0.0;
        return;
    }

    // ---- phase A1: stable rank + per-object params + separable gsum (all in LDS)
    if (on) {
        // stable ascending rank == jnp.argsort(-log_a)
        int r = 0;
        for (int j = 0; j < NOBJ; ++j) {
            float kj = skey[j];
            if (kj < key || (kj == key && j < tid)) r++;
        }
        bool valid = (clsv >= 0.f);

        float cx = truncf((x1 + x2) * 0.125f);       // *0.5/DOWN, DOWN=4
        float cy = truncf((y1 + y2) * 0.125f);
        float fx1 = fminf(fmaxf(x1*0.25f, 0.f), WW - 1.f);
        float fx2 = fminf(fmaxf(x2*0.25f, 0.f), WW - 1.f);
        float fy1 = fminf(fmaxf(y1*0.25f, 0.f), HH - 1.f);
        float fy2 = fminf(fmaxf(y2*0.25f, 0.f), HH - 1.f);
        int hr = (int)((fy2 - fy1) * 0.5f * 0.54f);  // trunc matches astype(int32)
        int wr = (int)((fx2 - fx1) * 0.5f * 0.54f);
        float sx = (float)(2*wr + 1) / 6.0f;
        float sy = (float)(2*hr + 1) / 6.0f;
        float ivx = 1.f / (2.f * sx * sx);
        float ivy = 1.f / (2.f * sy * sy);

        // separable gaussian sum (gx carries the valid mask, as in reference)
        int yc = (int)cy, xc = (int)cx;
        float sgy = 0.f;
        {
            int ya = max(0, yc - hr), yb = min(HH - 1, yc + hr);
            for (int y = ya; y <= yb; ++y) {
                float dy = (float)y - cy;
                sgy += __expf(-(dy*dy) * ivy);
            }
        }
        float sgx = 0.f;
        if (valid) {
            int xa = max(0, xc - wr), xb = min(WW - 1, xc + wr);
            for (int x = xa; x <= xb; ++x) {
                float dx = (float)x - cx;
                sgx += __expf(-(dx*dx) * ivx);
            }
        }
        float gsum = fmaxf(sgy * sgx, 1e-12f);
        int cls_i = min(max((int)clsv, 0), NC - 1);

        sg0[r] = make_float4(cx, cy, (float)wr, (float)hr);
        sg1[r] = make_float4(ivx, ivy, __int_as_float(cls_i), 1.f / gsum);
        sg2[r] = make_float4(x1, y1, x2, y2);
    }
    __syncthreads();

    float4 g0i = sg0[i], g1i = sg1[i], g2i = sg2[i];
    float cx = g0i.x, cy = g0i.y;
    int wr = (int)g0i.z, hr = (int)g0i.w;
    float ivx = g1i.x, ivy = g1i.y;
    int ci = __float_as_int(g1i.z);
    float ivg = g1i.w;
    int xc = (int)cx, yc = (int)cy;
    int xa = max(0, xc - wr), xb = min(WW - 1, xc + wr);
    int ya = max(0, yc - hr), yb = min(HH - 1, yc + hr);
    int wN = xb - xa + 1, hN = yb - ya + 1, npix = wN * hN;

    // ---- candidate lists: objects whose (unclipped) window intersects mine ----
    if (tid < nvb && tid != i) {
        float4 g0 = sg0[tid];
        bool inter = (g0.x - g0.z <= (float)xb) && (g0.x + g0.z >= (float)xa) &&
                     (g0.y - g0.w <= (float)yb) && (g0.y + g0.w >= (float)ya);
        if (inter) {
            int cj = __float_as_int(sg1[tid].z);
            if (tid < i) {
                if (cj == ci) prevl[atomicAdd(&s_np, 1)] = tid;
            } else {
                nextl[atomicAdd(&s_nn, 1)] = tid | ((cj == ci) ? 0x10000 : 0);
            }
        }
    }
    __syncthreads();
    int np = s_np, nn = s_nn;

    float posl = 0.f, negl = 0.f, npos = 0.f, wsum = 0.f, gl = 0.f;

    for (int t0 = tid; t0 < npix; t0 += 256) {   // npix <= 225 here: single iteration
        int ry = t0 / wN;
        int px = xa + (t0 - ry * wN);
        int py = ya + ry;
        float fx = (float)px, fy = (float)py;

        // first covering object of class ci at this pixel? (order-free existence)
        bool first = true;
        for (int k = 0; k < np; ++k) {
            float4 g0 = sg0[prevl[k]];
            if (fabsf(fx - g0.x) <= g0.z && fabsf(fy - g0.y) <= g0.w) first = false;
        }

        float dxi = fx - cx, dyi = fy - cy;
        float gi = __expf(-(dxi*dxi) * ivx) * __expf(-(dyi*dyi) * ivy);
        float t = gi;
        bool is_owner = true;        // owner = largest covering sorted idx
        for (int k = 0; k < nn; ++k) {
            int e = nextl[k];
            int j = e & 0xFFFF;
            float4 g0 = sg0[j];
            float dxj = fx - g0.x, dyj = fy - g0.y;
            if (fabsf(dxj) <= g0.z && fabsf(dyj) <= g0.w) {
                is_owner = false;
                if ((e & 0x10000) && first) {
                    float4 g1 = sg1[j];
                    float gj = __expf(-(dxj*dxj) * g1.x) * __expf(-(dyj*dyj) * g1.y);
                    t = fmaxf(t, gj);
                }
            }
        }

        if (first) {
            // correction vs. dense tgt=0 baseline for (pixel, class ci)
            float h = heat[((size_t)b * NC + ci) * HW + (size_t)py * WW + px];
            float e = __expf(-h);
            float q = 1.f + e;
            float lq = __logf(q);
            float p = 1.f / q;
            float basef = (h + lq) * p * p;
            if (t == 1.0f) {
                posl += lq * (1.f - p) * (1.f - p);   // -log(pred)*(1-pred)^2
                negl -= basef;
                npos += 1.f;
            } else {
                float u1 = 1.f - t;
                float u2 = u1 * u1;
                negl += basef * (u2 * u2 - 1.f);      // weight (1-t)^4 instead of 1
            }
        }

        if (is_owner) {
            float w = gi * ivg;
            size_t po = (size_t)py * WW + px;
            const float* whb = wh + (size_t)b * 4 * HW + po;
            float w0 = whb[0], w1 = whb[HW], w2 = whb[2*HW], w3 = whb[3*HW];
            float bx = fx * 4.f, by = fy * 4.f;
            float px1 = bx - w0, py1 = by - w1, px2 = bx + w2, py2 = by + w3;
            float tx1 = g2i.x, ty1 = g2i.y, tx2 = g2i.z, ty2 = g2i.w;
            float ltx = fmaxf(px1, tx1), lty = fmaxf(py1, ty1);
            float rbx = fminf(px2, tx2), rby = fminf(py2, ty2);
            float iw = fmaxf(rbx - ltx + 1.f, 0.f), ih = fmaxf(rby - lty + 1.f, 0.f);
            float e1x = fminf(px1, tx1), e1y = fminf(py1, ty1);
            float e2x = fmaxf(px2, tx2), e2y = fmaxf(py2, ty2);
            float ew = fmaxf(e2x - e1x + 1.f, 0.f), eh = fmaxf(e2y - e1y + 1.f, 0.f);
            float ov = iw * ih;
            float ap = (px2 - px1 + 1.f) * (py2 - py1 + 1.f);
            float ag = (tx2 - tx1 + 1.f) * (ty2 - ty1 + 1.f);
            float u = ap + ag - ov;
            float iou = ov / u;
            float ea = ew * eh;
            float giou = iou - (ea - u) / ea;
            wsum += w;
            gl += (1.f - giou) * w;
        }
    }

    // reduce 5 values over 4 waves -> plain stores to this block's unique slot
    float vals[5] = { posl, negl, npos, wsum, gl };
    #pragma unroll
    for (int k = 0; k < 5; ++k) {
        float v = vals[k];
        for (int off = 32; off > 0; off >>= 1) v += __shfl_down(v, off, 64);
        vals[k] = v;
    }
    __shared__ float red[5][4];
    int lane = tid & 63, wv = tid >> 6;
    if (lane == 0) {
        #pragma unroll
        for (int k = 0; k < 5; ++k) red[k][wv] = vals[k];
    }
    __syncthreads();
    if (tid == 0) {
        #pragma unroll
        for (int k = 0; k < 5; ++k)
            sacc[k] = (double)red[k][0] + (double)red[k][1] + (double)red[k][2] + (double)red[k][3];
    }
}

// ---------------- Kernel 2: finalize (parallel reduction over all partials) ----------
__global__ __launch_bounds__(512) void finalize_kernel(const double* __restrict__ part,
                                                       float* __restrict__ out) {
    int tid = threadIdx.x;
    double v[6] = {0,0,0,0,0,0};     // dneg, posl, negc, npos, wsum, gl
    for (int d = tid; d < DENSE_BLOCKS; d += 512) v[0] += part[d];
    for (int s = tid; s < SCATTER_BLOCKS; s += 512) {
        const double* p = part + SACC_OFF + (size_t)s * 5;
        v[1] += p[0]; v[2] += p[1]; v[3] += p[2]; v[4] += p[3]; v[5] += p[4];
    }
    #pragma unroll
    for (int k = 0; k < 6; ++k) {
        double x = v[k];
        for (int off = 32; off > 0; off >>= 1) x += __shfl_down(x, off, 64);
        v[k] = x;
    }
    __shared__ double red[6][8];
    int lane = tid & 63, wv = tid >> 6;
    if (lane == 0) {
        #pragma unroll
        for (int k = 0; k < 6; ++k) red[k][wv] = v[k];
    }
    __syncthreads();
    if (tid == 0) {
        double s[6];
        #pragma unroll
        for (int k = 0; k < 6; ++k) {
            double x = 0.0;
            for (int w = 0; w < 8; ++w) x += red[k][w];
            s[k] = x;
        }
        double neg = s[2] + s[0];
        double hm = (s[3] > 0.0) ? (s[1] + neg) / s[3] : neg;
        out[0] = (float)hm;                           // HM_W = 1.0
        out[1] = (float)(s[5] / (s[4] + 1e-4) * 0.1); // WH_W = 0.1
    }
}

extern "C" void kernel_launch(void* const* d_in, const int* in_sizes, int n_in,
                              void* d_out, int out_size, void* d_ws, size_t ws_size,
                              hipStream_t stream) {
    const float* heat = (const float*)d_in[0];   // (16,80,128,128)
    const float* wh   = (const float*)d_in[1];   // (16,4,128,128)
    const float* ann  = (const float*)d_in[2];   // (16,100,5)
    float* out = (float*)d_out;

    double* part = (double*)d_ws;

    main_kernel<<<TOTAL_BLOCKS, 256, 0, stream>>>(heat, wh, ann, part);
    finalize_kernel<<<1, 512, 0, stream>>>(part, out);
}